// Round 3
// baseline (204.962 us; speedup 1.0000x reference)
//
#include <hip/hip_runtime.h>
#include <cmath>

#define NEG_INF (-1.0e30f)

static constexpr int B = 256;
static constexpr int N = 65536;
static constexpr int THREADS = 256;          // 4 waves/block
static constexpr float C_OFF = 40.96f;       // = 64 * 0.8^2, upper bound of both logits
static constexpr float PAD = 0.2f;           // exact pad: logit(v<=0.2) == 0 == logit(0.2)

__device__ __forceinline__ float wave_sum_f(float v) {
#pragma unroll
  for (int off = 32; off >= 1; off >>= 1) v += __shfl_xor(v, off, 64);
  return v;
}

// Merge this lane's descending-sorted 16-list with XOR-partner lane's list,
// keeping the top-16 of the union (bitonic top-k merge).
__device__ __forceinline__ void merge_lists_shfl(float t[16], int off) {
  float b[16];
#pragma unroll
  for (int i = 0; i < 16; ++i) b[i] = __shfl_xor(t[i], off, 64);
  float c[16];
#pragma unroll
  for (int i = 0; i < 16; ++i) c[i] = fmaxf(t[i], b[15 - i]);
#pragma unroll
  for (int s = 8; s >= 1; s >>= 1) {
#pragma unroll
    for (int i = 0; i < 16; ++i) {
      if ((i & s) == 0) {
        float lo = c[i], hi = c[i + s];
        c[i] = fmaxf(lo, hi);
        c[i + s] = fminf(lo, hi);
      }
    }
  }
#pragma unroll
  for (int i = 0; i < 16; ++i) t[i] = c[i];
}

// Same top-16 merge, but between two register lists (no shuffle).
__device__ __forceinline__ void merge_lists_local(float a[16], const float b[16]) {
  float c[16];
#pragma unroll
  for (int i = 0; i < 16; ++i) c[i] = fmaxf(a[i], b[15 - i]);
#pragma unroll
  for (int s = 8; s >= 1; s >>= 1) {
#pragma unroll
    for (int i = 0; i < 16; ++i) {
      if ((i & s) == 0) {
        float lo = c[i], hi = c[i + s];
        c[i] = fmaxf(lo, hi);
        c[i + s] = fminf(lo, hi);
      }
    }
  }
#pragma unroll
  for (int i = 0; i < 16; ++i) a[i] = c[i];
}

__device__ __forceinline__ void process_elem(float s, float l, float& s_p,
                                             float& s_n, int& nn, float t[10]) {
  const bool pos = l > 0.5f;
  const bool neg = l < 0.25f;
  // logit_p = 64*relu(0.8-s)^2 ; logit_n = 64*relu(s-0.2)^2 (both in [0, 40.96])
  float d = pos ? (0.8f - s) : (s - 0.2f);
  float r = fmaxf(d, 0.f);
  float arg = __builtin_fmaf(64.f * r, r, -C_OFF);  // <= 0, finite for all s
  float e = __expf(arg);
  if (pos) s_p += e;
  if (neg) s_n += e;
  // wave-uniform negative count on the SALU (no per-lane VALU add)
  nn += (int)__popcll(__ballot(neg));
  if (neg & (s > t[9])) {  // maintain sorted-descending top-10 (floor 0.2 is exact)
    t[9] = s;
#pragma unroll
    for (int i = 9; i > 0; --i) {
      float a = t[i - 1], bb = t[i];
      t[i - 1] = fmaxf(a, bb);
      t[i] = fminf(a, bb);
    }
  }
}

// One block per (row, part). Writes partial {sum_p, sum_n, count_n, top16}.
template <int SPLIT>
__global__ void __launch_bounds__(THREADS, 8) ranking_partial_kernel(
    const float* __restrict__ sim, const float* __restrict__ label,
    float* __restrict__ ws_sp, float* __restrict__ ws_sn,
    int* __restrict__ ws_cnt, float* __restrict__ ws_top) {
  const int blk = blockIdx.x;
  const int row = blk / SPLIT;
  const int part = blk % SPLIT;
  const int tid = threadIdx.x;
  const size_t base4 = (size_t)row * (N / 4) + (size_t)part * (N / (4 * SPLIT));
  const float4* sim4 = reinterpret_cast<const float4*>(sim) + base4;
  const float4* lab4 = reinterpret_cast<const float4*>(label) + base4;

  float s_p = 0.f, s_n = 0.f;
  int nn = 0;  // wave-uniform (ballot-popc accumulated)
  float t[10];
#pragma unroll
  for (int i = 0; i < 10; ++i) t[i] = PAD;

  constexpr int ITER = N / 4 / THREADS / SPLIT;
  // Batch 4 iterations of loads (8 dwordx4 in flight), then process.
#pragma unroll
  for (int it = 0; it < ITER; it += 4) {
    float4 sv[4], lv[4];
#pragma unroll
    for (int j = 0; j < 4; ++j) {
      sv[j] = sim4[(it + j) * THREADS + tid];
      lv[j] = lab4[(it + j) * THREADS + tid];
    }
#pragma unroll
    for (int j = 0; j < 4; ++j) {
      process_elem(sv[j].x, lv[j].x, s_p, s_n, nn, t);
      process_elem(sv[j].y, lv[j].y, s_p, s_n, nn, t);
      process_elem(sv[j].z, lv[j].z, s_p, s_n, nn, t);
      process_elem(sv[j].w, lv[j].w, s_p, s_n, nn, t);
    }
  }

  // expand to 16-list for bitonic merges (pad 0.2 keeps descending order)
  float tl[16];
#pragma unroll
  for (int i = 0; i < 10; ++i) tl[i] = t[i];
#pragma unroll
  for (int i = 10; i < 16; ++i) tl[i] = PAD;

  // intra-wave reductions
  s_p = wave_sum_f(s_p);
  s_n = wave_sum_f(s_n);
#pragma unroll
  for (int off = 1; off < 64; off <<= 1) merge_lists_shfl(tl, off);

  __shared__ float ls_p[4], ls_n[4];
  __shared__ int ls_c[4];
  __shared__ float ltop[4][16];
  const int wave = tid >> 6, lane = tid & 63;
  if (lane == 0) {
    ls_p[wave] = s_p;
    ls_n[wave] = s_n;
    ls_c[wave] = nn;
#pragma unroll
    for (int i = 0; i < 16; ++i) ltop[wave][i] = tl[i];
  }
  __syncthreads();

  if (wave == 0) {
    // lanes 0..3 each hold one wave's top-16; butterfly-merge them
    float m[16];
    if (lane < 4) {
#pragma unroll
      for (int i = 0; i < 16; ++i) m[i] = ltop[lane][i];
    } else {
#pragma unroll
      for (int i = 0; i < 16; ++i) m[i] = PAD;
    }
    merge_lists_shfl(m, 1);
    merge_lists_shfl(m, 2);

    float sp = (lane < 4) ? ls_p[lane] : 0.f;
    float sn = (lane < 4) ? ls_n[lane] : 0.f;
    int cn = (lane < 4) ? ls_c[lane] : 0;
    sp = wave_sum_f(sp);
    sn = wave_sum_f(sn);
#pragma unroll
    for (int off = 32; off >= 1; off >>= 1) cn += __shfl_xor(cn, off, 64);

    if (lane == 0) {
      ws_sp[blk] = sp;
      ws_sn[blk] = sn;
      ws_cnt[blk] = cn;
#pragma unroll
      for (int i = 0; i < 16; ++i) ws_top[blk * 16 + i] = m[i];
    }
  }
}

// One block, 256 threads: thread r combines the SPLIT partials of row r,
// computes the row loss, then the block reduces to the final mean.
template <int SPLIT>
__global__ void __launch_bounds__(256) combine_kernel(
    const float* __restrict__ ws_sp, const float* __restrict__ ws_sn,
    const int* __restrict__ ws_cnt, const float* __restrict__ ws_top,
    float* __restrict__ out) {
  const int r = threadIdx.x;
  const int p0 = r * SPLIT;

  float a[16];
#pragma unroll
  for (int i = 0; i < 16; ++i) a[i] = ws_top[p0 * 16 + i];
#pragma unroll
  for (int k = 1; k < SPLIT; ++k) {
    float b[16];
#pragma unroll
    for (int i = 0; i < 16; ++i) b[i] = ws_top[(p0 + k) * 16 + i];
    merge_lists_local(a, b);  // a = running top-16, sorted descending
  }

  float sp = 0.f, sn = 0.f;
  int cn = 0;
#pragma unroll
  for (int k = 0; k < SPLIT; ++k) {
    sp += ws_sp[p0 + k];
    sn += ws_sn[p0 + k];
    cn += ws_cnt[p0 + k];
  }

  // any positives <=> sp > 0 (each pos term >= exp(-40.96) > 0)
  float lse_p = (sp > 0.f) ? (C_OFF + __logf(sp)) : 0.f;
  float lse_n_all = (sn > 0.f) ? (C_OFF + __logf(sn)) : NEG_INF;

  // top-10 logsumexp (a[0..9] = top-10 negative sims; pad 0.2 -> logit 0, exact)
  float mx = NEG_INF;
  float lg[10];
#pragma unroll
  for (int i = 0; i < 10; ++i) {
    float v = a[i];
    float al = fmaxf(v - 0.2f, 0.f);
    float lo = al * (v - 0.2f) * 64.f;
    lg[i] = lo;
    mx = fmaxf(mx, lo);
  }
  float ss = 0.f;
#pragma unroll
  for (int i = 0; i < 10; ++i) ss += __expf(lg[i] - mx);
  float lse_n_top = mx + __logf(ss);

  float lse_n = (cn > 20) ? lse_n_top : lse_n_all;
  float x = lse_n + lse_p;
  // softplus(x) = max(x,0) + log1p(exp(-|x|))
  float loss = fmaxf(x, 0.f) + log1pf(__expf(-fabsf(x)));

  // block reduction (256 threads = 4 waves)
  float v = wave_sum_f(loss);
  __shared__ float wsh[4];
  if ((r & 63) == 0) wsh[r >> 6] = v;
  __syncthreads();
  if (r == 0) out[0] = (wsh[0] + wsh[1] + wsh[2] + wsh[3]) * (1.0f / 256.0f);
}

template <int SPLIT>
static void launch_all(const float* sim, const float* label, float* out,
                       float* wsf, hipStream_t stream) {
  constexpr int P = B * SPLIT;
  float* ws_sp = wsf;
  float* ws_sn = wsf + P;
  float* ws_top = wsf + 2 * P;
  int* ws_cnt = (int*)(wsf + 2 * P + P * 16);
  ranking_partial_kernel<SPLIT><<<dim3(P), dim3(THREADS), 0, stream>>>(
      sim, label, ws_sp, ws_sn, ws_cnt, ws_top);
  combine_kernel<SPLIT><<<dim3(1), dim3(256), 0, stream>>>(ws_sp, ws_sn, ws_cnt,
                                                           ws_top, out);
}

extern "C" void kernel_launch(void* const* d_in, const int* in_sizes, int n_in,
                              void* d_out, int out_size, void* d_ws, size_t ws_size,
                              hipStream_t stream) {
  const float* sim = (const float*)d_in[0];
  const float* label = (const float*)d_in[1];
  float* out = (float*)d_out;
  float* wsf = (float*)d_ws;

  auto need = [](int split) { return (size_t)B * split * 19 * sizeof(float); };
  if (ws_size >= need(8)) {
    launch_all<8>(sim, label, out, wsf, stream);
  } else if (ws_size >= need(4)) {
    launch_all<4>(sim, label, out, wsf, stream);
  } else {
    launch_all<2>(sim, label, out, wsf, stream);
  }
}

// Round 4
// 155.374 us; speedup vs baseline: 1.3192x; 1.3192x over previous
//
#include <hip/hip_runtime.h>
#include <cmath>

#define NEG_INF (-1.0e30f)

static constexpr int B = 256;
static constexpr int N = 65536;
static constexpr int THREADS = 256;          // 4 waves/block
static constexpr float C_OFF = 40.96f;       // = 64 * 0.8^2, upper bound of both logits
static constexpr float PAD = 0.2f;           // exact pad: logit(v<=0.2) == 0 == logit(0.2)

__device__ __forceinline__ float wave_sum_f(float v) {
#pragma unroll
  for (int off = 32; off >= 1; off >>= 1) v += __shfl_xor(v, off, 64);
  return v;
}

// Merge this lane's descending-sorted 16-list with XOR-partner lane's list,
// keeping the top-16 of the union (bitonic top-k merge).
__device__ __forceinline__ void merge_lists_shfl(float t[16], int off) {
  float b[16];
#pragma unroll
  for (int i = 0; i < 16; ++i) b[i] = __shfl_xor(t[i], off, 64);
  float c[16];
#pragma unroll
  for (int i = 0; i < 16; ++i) c[i] = fmaxf(t[i], b[15 - i]);
#pragma unroll
  for (int s = 8; s >= 1; s >>= 1) {
#pragma unroll
    for (int i = 0; i < 16; ++i) {
      if ((i & s) == 0) {
        float lo = c[i], hi = c[i + s];
        c[i] = fmaxf(lo, hi);
        c[i + s] = fminf(lo, hi);
      }
    }
  }
#pragma unroll
  for (int i = 0; i < 16; ++i) t[i] = c[i];
}

// Same top-16 merge, but between two register lists (no shuffle).
__device__ __forceinline__ void merge_lists_local(float a[16], const float b[16]) {
  float c[16];
#pragma unroll
  for (int i = 0; i < 16; ++i) c[i] = fmaxf(a[i], b[15 - i]);
#pragma unroll
  for (int s = 8; s >= 1; s >>= 1) {
#pragma unroll
    for (int i = 0; i < 16; ++i) {
      if ((i & s) == 0) {
        float lo = c[i], hi = c[i + s];
        c[i] = fmaxf(lo, hi);
        c[i + s] = fminf(lo, hi);
      }
    }
  }
#pragma unroll
  for (int i = 0; i < 16; ++i) a[i] = c[i];
}

__device__ __forceinline__ void process_elem(float s, float l, float& s_p,
                                             float& s_n, int& nn, float t[10]) {
  const bool pos = l > 0.5f;
  const bool neg = l < 0.25f;
  // logit_p = 64*relu(0.8-s)^2 ; logit_n = 64*relu(s-0.2)^2 (both in [0, 40.96])
  float d = pos ? (0.8f - s) : (s - 0.2f);
  float r = fmaxf(d, 0.f);
  float arg = __builtin_fmaf(64.f * r, r, -C_OFF);  // <= 0, finite for all s
  float e = __expf(arg);
  if (pos) s_p += e;
  if (neg) s_n += e;
  // wave-uniform negative count on the SALU (no per-lane VALU add)
  nn += (int)__popcll(__ballot(neg));
  // sorted-descending top-10 insert. se=PAD for non-neg never triggers
  // (t[9] >= PAD invariant). Insert via v_med3: r[i] = med3(se, told[i-1], told[i])
  float se = neg ? s : PAD;
  if (se > t[9]) {
    float prev = t[0];
    t[0] = fmaxf(t[0], se);
#pragma unroll
    for (int i = 1; i < 10; ++i) {
      float cur = t[i];
      t[i] = __builtin_amdgcn_fmed3f(se, prev, cur);
      prev = cur;
    }
  }
}

// One block per (row, part). Writes partial {sum_p, sum_n, count_n, top16}.
template <int SPLIT>
__global__ void __launch_bounds__(THREADS, 4) ranking_partial_kernel(
    const float* __restrict__ sim, const float* __restrict__ label,
    float* __restrict__ ws_sp, float* __restrict__ ws_sn,
    int* __restrict__ ws_cnt, float* __restrict__ ws_top) {
  const int blk = blockIdx.x;
  const int row = blk / SPLIT;
  const int part = blk % SPLIT;
  const int tid = threadIdx.x;
  const size_t base4 = (size_t)row * (N / 4) + (size_t)part * (N / (4 * SPLIT));
  const float4* sim4 = reinterpret_cast<const float4*>(sim) + base4;
  const float4* lab4 = reinterpret_cast<const float4*>(label) + base4;

  float s_p = 0.f, s_n = 0.f;
  int nn = 0;  // wave-uniform (ballot-popc accumulated)
  float t[10];
#pragma unroll
  for (int i = 0; i < 10; ++i) t[i] = PAD;

  constexpr int ITER = N / 4 / THREADS / SPLIT;  // 8 at SPLIT=8
  // Batch 4 iterations of loads (8 dwordx4 in flight), then process.
#pragma unroll
  for (int it = 0; it < ITER; it += 4) {
    float4 sv[4], lv[4];
#pragma unroll
    for (int j = 0; j < 4; ++j) {
      sv[j] = sim4[(it + j) * THREADS + tid];
      lv[j] = lab4[(it + j) * THREADS + tid];
    }
#pragma unroll
    for (int j = 0; j < 4; ++j) {
      process_elem(sv[j].x, lv[j].x, s_p, s_n, nn, t);
      process_elem(sv[j].y, lv[j].y, s_p, s_n, nn, t);
      process_elem(sv[j].z, lv[j].z, s_p, s_n, nn, t);
      process_elem(sv[j].w, lv[j].w, s_p, s_n, nn, t);
    }
  }

  // expand to 16-list for bitonic merges (pad 0.2 keeps descending order)
  float tl[16];
#pragma unroll
  for (int i = 0; i < 10; ++i) tl[i] = t[i];
#pragma unroll
  for (int i = 10; i < 16; ++i) tl[i] = PAD;

  // intra-wave reductions
  s_p = wave_sum_f(s_p);
  s_n = wave_sum_f(s_n);
#pragma unroll
  for (int off = 1; off < 64; off <<= 1) merge_lists_shfl(tl, off);

  __shared__ float ls_p[4], ls_n[4];
  __shared__ int ls_c[4];
  __shared__ float ltop[4][16];
  const int wave = tid >> 6, lane = tid & 63;
  if (lane == 0) {
    ls_p[wave] = s_p;
    ls_n[wave] = s_n;
    ls_c[wave] = nn;
#pragma unroll
    for (int i = 0; i < 16; ++i) ltop[wave][i] = tl[i];
  }
  __syncthreads();

  if (wave == 0) {
    // lanes 0..3 each hold one wave's top-16; butterfly-merge them
    float m[16];
    if (lane < 4) {
#pragma unroll
      for (int i = 0; i < 16; ++i) m[i] = ltop[lane][i];
    } else {
#pragma unroll
      for (int i = 0; i < 16; ++i) m[i] = PAD;
    }
    merge_lists_shfl(m, 1);
    merge_lists_shfl(m, 2);

    float sp = (lane < 4) ? ls_p[lane] : 0.f;
    float sn = (lane < 4) ? ls_n[lane] : 0.f;
    int cn = (lane < 4) ? ls_c[lane] : 0;
    sp = wave_sum_f(sp);
    sn = wave_sum_f(sn);
#pragma unroll
    for (int off = 32; off >= 1; off >>= 1) cn += __shfl_xor(cn, off, 64);

    if (lane == 0) {
      ws_sp[blk] = sp;
      ws_sn[blk] = sn;
      ws_cnt[blk] = cn;
#pragma unroll
      for (int i = 0; i < 16; ++i) ws_top[blk * 16 + i] = m[i];
    }
  }
}

// One block, 256 threads: thread r combines the SPLIT partials of row r,
// computes the row loss, then the block reduces to the final mean.
template <int SPLIT>
__global__ void __launch_bounds__(256) combine_kernel(
    const float* __restrict__ ws_sp, const float* __restrict__ ws_sn,
    const int* __restrict__ ws_cnt, const float* __restrict__ ws_top,
    float* __restrict__ out) {
  const int r = threadIdx.x;
  const int p0 = r * SPLIT;

  float a[16];
#pragma unroll
  for (int i = 0; i < 16; ++i) a[i] = ws_top[p0 * 16 + i];
#pragma unroll
  for (int k = 1; k < SPLIT; ++k) {
    float b[16];
#pragma unroll
    for (int i = 0; i < 16; ++i) b[i] = ws_top[(p0 + k) * 16 + i];
    merge_lists_local(a, b);  // a = running top-16, sorted descending
  }

  float sp = 0.f, sn = 0.f;
  int cn = 0;
#pragma unroll
  for (int k = 0; k < SPLIT; ++k) {
    sp += ws_sp[p0 + k];
    sn += ws_sn[p0 + k];
    cn += ws_cnt[p0 + k];
  }

  // any positives <=> sp > 0 (each pos term >= exp(-40.96) > 0)
  float lse_p = (sp > 0.f) ? (C_OFF + __logf(sp)) : 0.f;
  float lse_n_all = (sn > 0.f) ? (C_OFF + __logf(sn)) : NEG_INF;

  // top-10 logsumexp (a[0..9] = top-10 negative sims; pad 0.2 -> logit 0, exact)
  float mx = NEG_INF;
  float lg[10];
#pragma unroll
  for (int i = 0; i < 10; ++i) {
    float v = a[i];
    float al = fmaxf(v - 0.2f, 0.f);
    float lo = al * (v - 0.2f) * 64.f;
    lg[i] = lo;
    mx = fmaxf(mx, lo);
  }
  float ss = 0.f;
#pragma unroll
  for (int i = 0; i < 10; ++i) ss += __expf(lg[i] - mx);
  float lse_n_top = mx + __logf(ss);

  float lse_n = (cn > 20) ? lse_n_top : lse_n_all;
  float x = lse_n + lse_p;
  // softplus(x) = max(x,0) + log1p(exp(-|x|))
  float loss = fmaxf(x, 0.f) + log1pf(__expf(-fabsf(x)));

  // block reduction (256 threads = 4 waves)
  float v = wave_sum_f(loss);
  __shared__ float wsh[4];
  if ((r & 63) == 0) wsh[r >> 6] = v;
  __syncthreads();
  if (r == 0) out[0] = (wsh[0] + wsh[1] + wsh[2] + wsh[3]) * (1.0f / 256.0f);
}

template <int SPLIT>
static void launch_all(const float* sim, const float* label, float* out,
                       float* wsf, hipStream_t stream) {
  constexpr int P = B * SPLIT;
  float* ws_sp = wsf;
  float* ws_sn = wsf + P;
  float* ws_top = wsf + 2 * P;
  int* ws_cnt = (int*)(wsf + 2 * P + P * 16);
  ranking_partial_kernel<SPLIT><<<dim3(P), dim3(THREADS), 0, stream>>>(
      sim, label, ws_sp, ws_sn, ws_cnt, ws_top);
  combine_kernel<SPLIT><<<dim3(1), dim3(256), 0, stream>>>(ws_sp, ws_sn, ws_cnt,
                                                           ws_top, out);
}

extern "C" void kernel_launch(void* const* d_in, const int* in_sizes, int n_in,
                              void* d_out, int out_size, void* d_ws, size_t ws_size,
                              hipStream_t stream) {
  const float* sim = (const float*)d_in[0];
  const float* label = (const float*)d_in[1];
  float* out = (float*)d_out;
  float* wsf = (float*)d_ws;

  auto need = [](int split) { return (size_t)B * split * 19 * sizeof(float); };
  if (ws_size >= need(8)) {
    launch_all<8>(sim, label, out, wsf, stream);
  } else if (ws_size >= need(4)) {
    launch_all<4>(sim, label, out, wsf, stream);
  } else {
    launch_all<2>(sim, label, out, wsf, stream);
  }
}